// Round 1
// baseline (288.705 us; speedup 1.0000x reference)
//
#include <hip/hip_runtime.h>

#define IRE (1.0f / 400.0f)

constexpr int W  = 512;
constexpr int H  = 512;
constexpr int NB = 64;
constexpr int TR = 32;                  // rows per block tile
constexpr int TILES = H / TR;           // 16
constexpr int NBLK  = NB * TILES;       // 1024 blocks = exactly 4/CU on 256 CUs
constexpr int NSLOT = 5;                // LDS row-ring depth (single-barrier safe: reuse distance 2 iters)

// LDS ring: 5 slots x 4 arrays x 512 floats = 40960 B exactly -> 4 blocks/CU = 160 KiB exact fit.

__device__ __forceinline__ void residuals3(
    float um, float vm, float ul, float vl, float ur, float vr,
    float ub, float vb, float ut, float vt,
    float& mass, float& momu, float& momv)
{
    float dudx = (ur - ul) * 0.5f;
    float dvdy = (vt - vb) * 0.5f;
    float ru = ur + um, lu = ul + um, tu_ = ut + um, bu = ub + um;
    float rv = vr + vm, lv = vl + vm, tv_ = vt + vm, bv = vb + vm;
    float du2dx = 0.25f * (ru * ru - lu * lu);
    float duvdy = 0.25f * (tu_ * tv_ - bu * bv);
    float dv2dy = 0.25f * (tv_ * tv_ - bv * bv);
    float dvudx = 0.25f * (rv * ru - lv * lu);
    float dudx2 = ur - 2.0f * um + ul;
    float dudy2 = ut - 2.0f * um + ub;
    float dvdx2 = vr - 2.0f * vm + vl;
    float dvdy2 = vt - 2.0f * vm + vb;
    mass = dudx + dvdy;
    momu = du2dx + duvdy - (dudx2 + dudy2) * IRE;
    momv = dvudx + dv2dy - (dvdx2 + dvdy2) * IRE;
}

struct W8 { float c0, c1, lf, rt, u0, u1, d0, d1; };

__global__ __launch_bounds__(256, 4) void loss_main(
    const float* __restrict__ pred, const float* __restrict__ trut,
    double* __restrict__ partial)
{
    __shared__ __align__(16) float ring[NSLOT * 4 * W];   // 40960 B

    const int tid  = (int)threadIdx.x;
    const int lane = tid & 63;
    const int wv   = tid >> 6;           // wave id == array it stages (0:tu 1:tv 2:pu 3:pv)
    const int blk  = (int)blockIdx.x;
    const int tile = blk % TILES;
    const int b    = blk / TILES;
    const int r0   = tile * TR;

    const size_t CH = (size_t)H * W;
    const float* gbase = (wv < 2 ? trut : pred) + (size_t)b * 2 * CH + (size_t)(wv & 1) * CH;

    // async global->LDS: wave-uniform LDS dest (+lane*16 by HW), per-lane global src.
    // One wave stages its own array's full 2 KB row as 2x 1 KB instructions.
    auto stage_row = [&](int row, int slot) {
        row = row < 0 ? 0 : (row > H - 1 ? H - 1 : row);
        const float* src = gbase + (size_t)row * W + lane * 4;
        float* dst = &ring[(slot * 4 + wv) * W];
        __builtin_amdgcn_global_load_lds(
            (const __attribute__((address_space(1))) void*)src,
            (__attribute__((address_space(3))) void*)dst, 16, 0, 0);
        __builtin_amdgcn_global_load_lds(
            (const __attribute__((address_space(1))) void*)(src + 256),
            (__attribute__((address_space(3))) void*)(dst + 256), 16, 0, 0);
    };

    // prologue: rows r0-1, r0, r0+1 -> slots 0,1,2 (6 outstanding vmem / wave)
    stage_row(r0 - 1, 0);
    stage_row(r0,     1);
    stage_row(r0 + 1, 2);

    const int j0  = tid * 2;                          // this thread's 2 columns
    const int jm1 = (j0 == 0) ? 0 : j0 - 1;           // clamped (masked-out point only)
    const int jp2 = (j0 + 2 > W - 1) ? W - 1 : j0 + 2;

    float accMass = 0.0f, accMom = 0.0f, accL1 = 0.0f;

    int sTop = 0;                                     // slot of row r-1 (= s % 5)
    for (int s = 0; s < TR; ++s) {
        const int r = r0 + s;
        if (s < TR - 1) {
            int sSt = sTop + 3; if (sSt >= NSLOT) sSt -= NSLOT;   // slot last read at iter s-2
            stage_row(r + 2, sSt);
            // allow the 2 just-issued loads to stay in flight; everything older
            // (incl. row r+1) must have landed. lgkmcnt(0): retire our ds_reads
            // before the barrier so a peer's stage can't overwrite under them.
            // raw s_barrier, NOT __syncthreads() (that would drain vmcnt(0)).
            asm volatile("s_waitcnt vmcnt(2) lgkmcnt(0)\n\ts_barrier" ::: "memory");
        } else {
            asm volatile("s_waitcnt vmcnt(0) lgkmcnt(0)\n\ts_barrier" ::: "memory");
        }

        int sMid = sTop + 1; if (sMid >= NSLOT) sMid -= NSLOT;
        int sBot = sMid + 1; if (sBot >= NSLOT) sBot -= NSLOT;
        const float* top = &ring[sTop * 4 * W];
        const float* mid = &ring[sMid * 4 * W];
        const float* bot = &ring[sBot * 4 * W];

        W8 wtu, wtv, wpu, wpv;
        #define LOADA(dst, a) \
            dst.c0 = mid[(a)*W + j0]; dst.c1 = mid[(a)*W + j0 + 1]; \
            dst.lf = mid[(a)*W + jm1]; dst.rt = mid[(a)*W + jp2]; \
            dst.u0 = top[(a)*W + j0]; dst.u1 = top[(a)*W + j0 + 1]; \
            dst.d0 = bot[(a)*W + j0]; dst.d1 = bot[(a)*W + j0 + 1];
        LOADA(wtu, 0) LOADA(wtv, 1) LOADA(wpu, 2) LOADA(wpv, 3)
        #undef LOADA

        // L1 over every (row, col, channel): each row owned by exactly one block-iter
        accL1 += fabsf(wpu.c0 - wtu.c0) + fabsf(wpu.c1 - wtu.c1)
               + fabsf(wpv.c0 - wtv.c0) + fabsf(wpv.c1 - wtv.c1);

        if (r >= 1 && r <= H - 2) {                   // wave-uniform row mask
            float mT, uT, vT, mP, uP, vP;
            // point j0: ul/ur = prev/next ROW, ub/ut = left/right COL (matches ref)
            residuals3(wtu.c0, wtv.c0, wtu.u0, wtv.u0, wtu.d0, wtv.d0,
                       wtu.lf, wtv.lf, wtu.c1, wtv.c1, mT, uT, vT);
            residuals3(wpu.c0, wpv.c0, wpu.u0, wpv.u0, wpu.d0, wpv.d0,
                       wpu.lf, wpv.lf, wpu.c1, wpv.c1, mP, uP, vP);
            if (j0 >= 1) {                            // only thread 0 masked
                accMass += fabsf(mT - mP);
                accMom  += fabsf(uT - uP) + fabsf(vT - vP);
            }
            // point j0+1
            residuals3(wtu.c1, wtv.c1, wtu.u1, wtv.u1, wtu.d1, wtv.d1,
                       wtu.c0, wtv.c0, wtu.rt, wtv.rt, mT, uT, vT);
            residuals3(wpu.c1, wpv.c1, wpu.u1, wpv.u1, wpu.d1, wpv.d1,
                       wpu.c0, wpv.c0, wpu.rt, wpv.rt, mP, uP, vP);
            if (j0 + 1 <= W - 2) {                    // only thread 255 masked
                accMass += fabsf(mT - mP);
                accMom  += fabsf(uT - uP) + fabsf(vT - vP);
            }
        }
        sTop = sMid;
    }

    float res = 5.0f * accMass + 25.0f * accMom;
    float l1  = accL1;
    #pragma unroll
    for (int off = 32; off > 0; off >>= 1) {
        res += __shfl_down(res, off);
        l1  += __shfl_down(l1, off);
    }
    __syncthreads();                                  // loop done; safe to reuse ring LDS
    double* sred = (double*)ring;
    if (lane == 0) { sred[wv] = (double)res; sred[4 + wv] = (double)l1; }
    __syncthreads();
    if (tid == 0) {
        partial[(size_t)blk * 2 + 0] = sred[0] + sred[1] + sred[2] + sred[3];
        partial[(size_t)blk * 2 + 1] = sred[4] + sred[5] + sred[6] + sred[7];
    }
}

__global__ __launch_bounds__(256) void loss_final(
    const double* __restrict__ partial, float* __restrict__ out)
{
    __shared__ double sres[4], sl1[4];
    const int t = (int)threadIdx.x;
    double res = 0.0, l1 = 0.0;
    for (int i = t; i < NBLK; i += 256) {
        res += partial[(size_t)i * 2 + 0];
        l1  += partial[(size_t)i * 2 + 1];
    }
    #pragma unroll
    for (int off = 32; off > 0; off >>= 1) {
        res += __shfl_down(res, off);
        l1  += __shfl_down(l1, off);
    }
    const int wave = t >> 6;
    if ((t & 63) == 0) { sres[wave] = res; sl1[wave] = l1; }
    __syncthreads();
    if (t == 0) {
        res = sres[0] + sres[1] + sres[2] + sres[3];
        l1  = sl1[0] + sl1[1] + sl1[2] + sl1[3];
        const double nRes = 64.0 * 510.0 * 510.0;
        const double nL1  = 64.0 * 2.0 * 512.0 * 512.0;
        out[0] = (float)((res / nRes + l1 / nL1) / 3.0);
    }
}

extern "C" void kernel_launch(void* const* d_in, const int* in_sizes, int n_in,
                              void* d_out, int out_size, void* d_ws, size_t ws_size,
                              hipStream_t stream)
{
    const float* pred = (const float*)d_in[0];
    const float* trut = (const float*)d_in[1];
    double* partial = (double*)d_ws;   // 1024*2 doubles = 16 KB, written before read
    loss_main<<<NBLK, 256, 0, stream>>>(pred, trut, partial);
    loss_final<<<1, 256, 0, stream>>>(partial, (float*)d_out);
}

// Round 2
// 284.203 us; speedup vs baseline: 1.0158x; 1.0158x over previous
//
#include <hip/hip_runtime.h>

#define IRE (1.0f / 400.0f)

constexpr int W  = 512;
constexpr int H  = 512;
constexpr int NB = 64;
constexpr int TR = 32;                  // rows per block tile
constexpr int TILES = H / TR;           // 16
constexpr int NBLK  = NB * TILES;       // 1024 blocks = 4/CU
constexpr int NSLOT = 4;                // ring: 4 slots x 4 arrays x 512 f32 = 32768 B

// Slot protocol (1 barrier/iter, stage->wait->barrier->read):
//   slot(row x) = (x - r0 + 1) & 3.  Iter s stages row r+2 into slot (s+3)&3 and
//   ds-reads row r+1 from slot (s+2)&3.  A slot's previous tenant (row r0+s-2) was
//   ds-read at iter s-3; lgkmcnt(0) before each barrier retires those reads, and
//   at least one barrier separates last-read from re-stage => no overwrite race.
//   vmcnt(2) leaves only the just-issued 2 loads in flight, so the row published
//   by the barrier (staged last iter) is guaranteed landed by its stager.

__device__ __forceinline__ void residuals3(
    float um, float vm, float ul, float vl, float ur, float vr,
    float ub, float vb, float ut, float vt,
    float& mass, float& momu, float& momv)
{
    float dudx = (ur - ul) * 0.5f;
    float dvdy = (vt - vb) * 0.5f;
    float ru = ur + um, lu = ul + um, tu_ = ut + um, bu = ub + um;
    float rv = vr + vm, lv = vl + vm, tv_ = vt + vm, bv = vb + vm;
    float du2dx = 0.25f * (ru * ru - lu * lu);
    float duvdy = 0.25f * (tu_ * tv_ - bu * bv);
    float dv2dy = 0.25f * (tv_ * tv_ - bv * bv);
    float dvudx = 0.25f * (rv * ru - lv * lu);
    float dudx2 = ur - 2.0f * um + ul;
    float dudy2 = ut - 2.0f * um + ub;
    float dvdx2 = vr - 2.0f * vm + vl;
    float dvdy2 = vt - 2.0f * vm + vb;
    mass = dudx + dvdy;
    momu = du2dx + duvdy - (dudx2 + dudy2) * IRE;
    momv = dvudx + dv2dy - (dvdx2 + dvdy2) * IRE;
}

__global__ __launch_bounds__(256, 4) void loss_main(
    const float* __restrict__ pred, const float* __restrict__ trut,
    double* __restrict__ partial)
{
    __shared__ __align__(16) float ring[NSLOT * 4 * W];   // 32768 B

    const int tid  = (int)threadIdx.x;
    const int lane = tid & 63;
    const int wv   = tid >> 6;           // wave stages array wv (0:tu 1:tv 2:pu 3:pv)
    const int blk  = (int)blockIdx.x;
    const int tile = blk % TILES;
    const int b    = blk / TILES;
    const int r0   = tile * TR;

    const size_t CH = (size_t)H * W;
    const float* gbase = (wv < 2 ? trut : pred) + (size_t)b * 2 * CH + (size_t)(wv & 1) * CH;

    // async global->LDS: wave-uniform LDS dest (+lane*16 by HW), per-lane global src
    auto stage_row = [&](int row, int slot) {
        row = row < 0 ? 0 : (row > H - 1 ? H - 1 : row);
        const float* src = gbase + (size_t)row * W + lane * 4;
        float* dst = &ring[slot * (4 * W) + wv * W];
        __builtin_amdgcn_global_load_lds(
            (const __attribute__((address_space(1))) void*)src,
            (__attribute__((address_space(3))) void*)dst, 16, 0, 0);
        __builtin_amdgcn_global_load_lds(
            (const __attribute__((address_space(1))) void*)(src + 256),
            (__attribute__((address_space(3))) void*)(dst + 256), 16, 0, 0);
    };

    // prologue: rows r0-1, r0, r0+1 -> slots 0,1,2
    stage_row(r0 - 1, 0);
    stage_row(r0,     1);
    stage_row(r0 + 1, 2);

    const int j0  = tid * 2;                          // this thread's 2 columns
    const int jm1 = (j0 == 0) ? 0 : j0 - 1;           // clamped (value masked anyway)
    const int jp2 = (j0 + 2 > W - 1) ? W - 1 : j0 + 2;

    float accMass = 0.0f, accMom = 0.0f, accL1 = 0.0f;

    // register window: rows r-1 (top: c only), r (mid: c + lf/rt), r+1 (bot, read per iter)
    float2 topc[4], midc[4], botc[4];
    float  midl[4], midr[4], botl[4], botr[4];

    // publish rows r0-1, r0 (first 4 of 6 loads done at vmcnt(2)); init window regs
    asm volatile("s_waitcnt vmcnt(2)\n\ts_barrier" ::: "memory");
    #pragma unroll
    for (int a = 0; a < 4; ++a) {
        const float* p0 = &ring[0 * (4 * W) + a * W];
        const float* p1 = &ring[1 * (4 * W) + a * W];
        topc[a] = *(const float2*)(p0 + j0);
        midc[a] = *(const float2*)(p1 + j0);
        midl[a] = p1[jm1];
        midr[a] = p1[jp2];
    }

    #pragma unroll 4
    for (int s = 0; s < TR; ++s) {
        const int r = r0 + s;
        if (s < TR - 1) {
            stage_row(r + 2, (s + 3) & 3);
            asm volatile("s_waitcnt vmcnt(2) lgkmcnt(0)\n\ts_barrier" ::: "memory");
        } else {
            asm volatile("s_waitcnt vmcnt(0) lgkmcnt(0)\n\ts_barrier" ::: "memory");
        }

        // single LDS visit per row: read row r+1 (bot) only
        const float* bp = &ring[((s + 2) & 3) * (4 * W)];
        #pragma unroll
        for (int a = 0; a < 4; ++a) {
            botc[a] = *(const float2*)(bp + a * W + j0);   // ds_read_b64, 2-way (free)
            botl[a] = bp[a * W + jm1];
            botr[a] = bp[a * W + jp2];
        }

        // L1 on mid row (each row owned by exactly one block-iter)
        accL1 += fabsf(midc[2].x - midc[0].x) + fabsf(midc[2].y - midc[0].y)
               + fabsf(midc[3].x - midc[1].x) + fabsf(midc[3].y - midc[1].y);

        if (r >= 1 && r <= H - 2) {                   // wave-uniform row mask
            float mT, uT, vT, mP, uP, vP;
            // point j0: ul/ur = prev/next ROW, ub/ut = left/right COL (matches ref)
            residuals3(midc[0].x, midc[1].x, topc[0].x, topc[1].x, botc[0].x, botc[1].x,
                       midl[0],   midl[1],   midc[0].y, midc[1].y, mT, uT, vT);
            residuals3(midc[2].x, midc[3].x, topc[2].x, topc[3].x, botc[2].x, botc[3].x,
                       midl[2],   midl[3],   midc[2].y, midc[3].y, mP, uP, vP);
            if (j0 >= 1) {                            // only thread 0 masked
                accMass += fabsf(mT - mP);
                accMom  += fabsf(uT - uP) + fabsf(vT - vP);
            }
            // point j0+1
            residuals3(midc[0].y, midc[1].y, topc[0].y, topc[1].y, botc[0].y, botc[1].y,
                       midc[0].x, midc[1].x, midr[0],   midr[1],   mT, uT, vT);
            residuals3(midc[2].y, midc[3].y, topc[2].y, topc[3].y, botc[2].y, botc[3].y,
                       midc[2].x, midc[3].x, midr[2],   midr[3],   mP, uP, vP);
            if (j0 + 1 <= W - 2) {                    // only thread 255 masked
                accMass += fabsf(mT - mP);
                accMom  += fabsf(uT - uP) + fabsf(vT - vP);
            }
        }

        // rotate window (unroll-4 lets the compiler rename most of these away)
        #pragma unroll
        for (int a = 0; a < 4; ++a) {
            topc[a] = midc[a];
            midc[a] = botc[a];
            midl[a] = botl[a];
            midr[a] = botr[a];
        }
    }

    float res = 5.0f * accMass + 25.0f * accMom;
    float l1  = accL1;
    #pragma unroll
    for (int off = 32; off > 0; off >>= 1) {
        res += __shfl_down(res, off);
        l1  += __shfl_down(l1, off);
    }
    __syncthreads();                                  // loop done; safe to reuse ring LDS
    double* sred = (double*)ring;
    if (lane == 0) { sred[wv] = (double)res; sred[4 + wv] = (double)l1; }
    __syncthreads();
    if (tid == 0) {
        partial[(size_t)blk * 2 + 0] = sred[0] + sred[1] + sred[2] + sred[3];
        partial[(size_t)blk * 2 + 1] = sred[4] + sred[5] + sred[6] + sred[7];
    }
}

__global__ __launch_bounds__(256) void loss_final(
    const double* __restrict__ partial, float* __restrict__ out)
{
    __shared__ double sres[4], sl1[4];
    const int t = (int)threadIdx.x;
    double res = 0.0, l1 = 0.0;
    for (int i = t; i < NBLK; i += 256) {
        res += partial[(size_t)i * 2 + 0];
        l1  += partial[(size_t)i * 2 + 1];
    }
    #pragma unroll
    for (int off = 32; off > 0; off >>= 1) {
        res += __shfl_down(res, off);
        l1  += __shfl_down(l1, off);
    }
    const int wave = t >> 6;
    if ((t & 63) == 0) { sres[wave] = res; sl1[wave] = l1; }
    __syncthreads();
    if (t == 0) {
        res = sres[0] + sres[1] + sres[2] + sres[3];
        l1  = sl1[0] + sl1[1] + sl1[2] + sl1[3];
        const double nRes = 64.0 * 510.0 * 510.0;
        const double nL1  = 64.0 * 2.0 * 512.0 * 512.0;
        out[0] = (float)((res / nRes + l1 / nL1) / 3.0);
    }
}

extern "C" void kernel_launch(void* const* d_in, const int* in_sizes, int n_in,
                              void* d_out, int out_size, void* d_ws, size_t ws_size,
                              hipStream_t stream)
{
    const float* pred = (const float*)d_in[0];
    const float* trut = (const float*)d_in[1];
    double* partial = (double*)d_ws;   // 1024*2 doubles = 16 KB, written before read
    loss_main<<<NBLK, 256, 0, stream>>>(pred, trut, partial);
    loss_final<<<1, 256, 0, stream>>>(partial, (float*)d_out);
}